// Round 6
// baseline (597.588 us; speedup 1.0000x reference)
//
#include <hip/hip_runtime.h>
#include <hip/hip_bf16.h>

#define C_CH 512
#define HW 16384
#define NB 8
#define TILE 128
#define BK 32                    // f32 k-elements per K-step
#define NTB 4                    // C_CH / TILE
#define NTILES 10                // upper-triangular 128^2 tiles
#define KSPLIT 8
#define KCHUNK (HW / KSPLIT)     // 2048
#define KSTEPS (KCHUNK / BK)     // 64 (even; loop steps by 2)
#define NGRAM 16
#define CC (C_CH * C_CH)
#define LOSS_BLOCKS 1024
#define GRID (NGRAM * KSPLIT * NTILES)   // 1280 = 8 * 160
#define PANEL_V8 (TILE * BK / 8)         // 512 bf16x8 slots = 8 KiB

typedef float f32x4 __attribute__((ext_vector_type(4)));
typedef __bf16 bf16x8 __attribute__((ext_vector_type(8)));

// raw barrier: drain LDS ops only; global loads STAY IN FLIGHT across it
// (__syncthreads would emit s_waitcnt vmcnt(0) and kill the pipeline)
#define BAR()                                                       \
    do {                                                            \
        asm volatile("s_waitcnt lgkmcnt(0)" ::: "memory");          \
        __builtin_amdgcn_s_barrier();                               \
    } while (0)

// LDS slot for (row R, k-chunk c in 0..3): zero-conflict pattern (measured R4/R5).
__device__ __forceinline__ int slot_of(int R, int c) {
    return (R >> 1) * 8 + ((((R & 1) << 2) + c) ^ ((R >> 1) & 7));
}

// Gram SYRK: 128x128 triangular tiles, 4 waves (2x2), bf16 LDS double-buffer,
// depth-2 reg pipeline with loads surviving barriers (counted vmcnt by compiler).
__global__ __launch_bounds__(256, 3) void gram_kernel(const float* __restrict__ det,
                                                      const float* __restrict__ sr,
                                                      float* __restrict__ gram) {
    // grouped chunked XCD swizzle: all tiles/ksplits of one g on one XCD -> the
    // 4x panel re-reads hit that XCD's L2
    const int lbid = ((int)blockIdx.x & 7) * (GRID / 8) + ((int)blockIdx.x >> 3);
    const int t = lbid % NTILES;
    const int gk = lbid / NTILES;        // = g*KSPLIT + ks
    const int ks = gk & (KSPLIT - 1);
    const int g = gk >> 3;
    const int tensor = g >> 3, b = g & 7;

    int ti = 0, tt = t;
    while (tt >= NTB - ti) { tt -= NTB - ti; ++ti; }
    const int tj = ti + tt;
    const bool diag = (ti == tj);

    const float* F = (tensor ? sr : det) + (size_t)b * C_CH * HW;
    const float* Abase = F + (size_t)(ti * TILE) * HW + ks * KCHUNK;
    const float* Bbase = F + (size_t)(tj * TILE) * HW + ks * KCHUNK;

    __shared__ bf16x8 lds[4 * PANEL_V8];   // [buf0 A|B][buf1 A|B] = 32 KiB

    const int tid = threadIdx.x;
    const int lane = tid & 63;
    const int wid = tid >> 6;
    const int wr = wid >> 1, wc = wid & 1;   // 2x2 waves -> per-wave 64x64

    // staging: panel = 128 rows x 4 chunks(8 f32) = 512 chunks / 256 thr = 2 each
    int goff[2], lslot[2];
    #pragma unroll
    for (int q = 0; q < 2; ++q) {
        int c = q * 256 + tid;
        int r = c >> 2, ch = c & 3;
        goff[q] = r * HW + ch * 8;
        lslot[q] = slot_of(r, ch);
    }

    // two named register sets (no runtime indexing -> no scratch)
    f32x4 a0[4], b0[4], a1[4], b1[4];
    auto LOAD0 = [&](int kt) {
        const int ko = kt * BK;
        #pragma unroll
        for (int q = 0; q < 2; ++q) {
            a0[2 * q]     = *(const f32x4*)(Abase + goff[q] + ko);
            a0[2 * q + 1] = *(const f32x4*)(Abase + goff[q] + ko + 4);
        }
        if (!diag) {
            #pragma unroll
            for (int q = 0; q < 2; ++q) {
                b0[2 * q]     = *(const f32x4*)(Bbase + goff[q] + ko);
                b0[2 * q + 1] = *(const f32x4*)(Bbase + goff[q] + ko + 4);
            }
        }
    };
    auto LOAD1 = [&](int kt) {
        const int ko = kt * BK;
        #pragma unroll
        for (int q = 0; q < 2; ++q) {
            a1[2 * q]     = *(const f32x4*)(Abase + goff[q] + ko);
            a1[2 * q + 1] = *(const f32x4*)(Abase + goff[q] + ko + 4);
        }
        if (!diag) {
            #pragma unroll
            for (int q = 0; q < 2; ++q) {
                b1[2 * q]     = *(const f32x4*)(Bbase + goff[q] + ko);
                b1[2 * q + 1] = *(const f32x4*)(Bbase + goff[q] + ko + 4);
            }
        }
    };
    auto WRITE0 = [&]() {            // set0 -> buf0
        bf16x8* As = lds;
        #pragma unroll
        for (int q = 0; q < 2; ++q) {
            bf16x8 h;
            #pragma unroll
            for (int i = 0; i < 4; ++i) { h[i] = (__bf16)a0[2 * q][i]; h[4 + i] = (__bf16)a0[2 * q + 1][i]; }
            As[lslot[q]] = h;
        }
        if (!diag) {
            bf16x8* Bs = As + PANEL_V8;
            #pragma unroll
            for (int q = 0; q < 2; ++q) {
                bf16x8 h;
                #pragma unroll
                for (int i = 0; i < 4; ++i) { h[i] = (__bf16)b0[2 * q][i]; h[4 + i] = (__bf16)b0[2 * q + 1][i]; }
                Bs[lslot[q]] = h;
            }
        }
    };
    auto WRITE1 = [&]() {            // set1 -> buf1
        bf16x8* As = lds + 2 * PANEL_V8;
        #pragma unroll
        for (int q = 0; q < 2; ++q) {
            bf16x8 h;
            #pragma unroll
            for (int i = 0; i < 4; ++i) { h[i] = (__bf16)a1[2 * q][i]; h[4 + i] = (__bf16)a1[2 * q + 1][i]; }
            As[lslot[q]] = h;
        }
        if (!diag) {
            bf16x8* Bs = As + PANEL_V8;
            #pragma unroll
            for (int q = 0; q < 2; ++q) {
                bf16x8 h;
                #pragma unroll
                for (int i = 0; i < 4; ++i) { h[i] = (__bf16)b1[2 * q][i]; h[4 + i] = (__bf16)b1[2 * q + 1][i]; }
                Bs[lslot[q]] = h;
            }
        }
    };

    f32x4 acc[4][4] = {};
    const int kg = lane >> 4;            // k-chunk of this lane's fragment
    const int l15 = lane & 15;
    auto COMPUTE = [&](const bf16x8* As) {
        const bf16x8* Bs = diag ? As : As + PANEL_V8;
        bf16x8 af[4], bfr[4];
        #pragma unroll
        for (int m = 0; m < 4; ++m) {
            int R = wr * 64 + m * 16 + l15;
            af[m] = As[slot_of(R, kg)];
        }
        #pragma unroll
        for (int n = 0; n < 4; ++n) {
            int R = wc * 64 + n * 16 + l15;
            bfr[n] = Bs[slot_of(R, kg)];
        }
        #pragma unroll
        for (int m = 0; m < 4; ++m)
            #pragma unroll
            for (int n = 0; n < 4; ++n)
                if (!diag || (wc * 64 + n * 16 + 16 > wr * 64 + m * 16))
                    acc[m][n] = __builtin_amdgcn_mfma_f32_16x16x32_bf16(af[m], bfr[n], acc[m][n], 0, 0, 0);
    };

    // prologue: issue tiles 0 and 1; write tile 0 (compiler waits only set0's loads)
    LOAD0(0);
    LOAD1(1);
    WRITE0();
    BAR();

    #pragma unroll 1
    for (int kt = 0; kt < KSTEPS; kt += 2) {
        // even step: compute buf0 (tile kt); write tile kt+1 (set1, in flight since kt-1)
        if (kt + 2 < KSTEPS) LOAD0(kt + 2);
        COMPUTE(lds);
        WRITE1();                         // counted vmcnt: set0 loads stay in flight
        BAR();
        // odd step: compute buf1 (tile kt+1); write tile kt+2 (set0)
        if (kt + 3 < KSTEPS) LOAD1(kt + 3);
        COMPUTE(lds + 2 * PANEL_V8);
        if (kt + 2 < KSTEPS) WRITE0();
        BAR();
    }

    // epilogue: C/D layout col=lane&15, row=(lane>>4)*4+j; skip below-diag frags
    float* gout = gram + (size_t)g * CC;
    const int rb = ti * TILE + wr * 64 + (kg << 2);
    const int cb = tj * TILE + wc * 64 + l15;
    #pragma unroll
    for (int m = 0; m < 4; ++m)
        #pragma unroll
        for (int n = 0; n < 4; ++n) {
            if (diag && (wc * 64 + n * 16 + 16 <= wr * 64 + m * 16)) continue;
            #pragma unroll
            for (int j = 0; j < 4; ++j)
                atomicAdd(&gout[(size_t)(rb + m * 16 + j) * C_CH + cb + n * 16], acc[m][n][j]);
        }
}

__global__ void norm_kernel(const float* __restrict__ gram, float* __restrict__ invn) {
    const int g = blockIdx.x, c = threadIdx.x;
    float v = gram[(size_t)g * CC + (size_t)c * C_CH + c];
    invn[g * C_CH + c] = 1.0f / sqrtf(v);
}

__global__ __launch_bounds__(256) void loss_kernel(const float* __restrict__ gram,
                                                   const float* __restrict__ invn,
                                                   float* __restrict__ partials) {
    const int tid = threadIdx.x;
    float s = 0.f;
    for (int idx = blockIdx.x * 256 + tid; idx < NB * CC; idx += LOSS_BLOCKS * 256) {
        int b = idx >> 18;
        int c = (idx >> 9) & 511;
        int d = idx & 511;
        int cc = c, dd = d;
        if (dd < cc) { int tmp = cc; cc = dd; dd = tmp; }   // upper triangle stored
        float gd = gram[(size_t)b * CC + (size_t)cc * C_CH + dd];
        float gs = gram[(size_t)(8 + b) * CC + (size_t)cc * C_CH + dd];
        float sd = gd * invn[b * C_CH + c] * invn[b * C_CH + d];
        float ss = gs * invn[(8 + b) * C_CH + c] * invn[(8 + b) * C_CH + d];
        float diff = sd - ss;
        s += diff * diff;
    }
    #pragma unroll
    for (int off = 32; off > 0; off >>= 1) s += __shfl_down(s, off, 64);
    __shared__ float red[4];
    if ((tid & 63) == 0) red[tid >> 6] = s;
    __syncthreads();
    if (tid == 0) partials[blockIdx.x] = red[0] + red[1] + red[2] + red[3];
}

__global__ void final_kernel(const float* __restrict__ partials, float* __restrict__ out) {
    const int tid = threadIdx.x;  // 256
    float s = 0.f;
    for (int i = tid; i < LOSS_BLOCKS; i += 256) s += partials[i];
    #pragma unroll
    for (int off = 32; off > 0; off >>= 1) s += __shfl_down(s, off, 64);
    __shared__ float red[4];
    if ((tid & 63) == 0) red[tid >> 6] = s;
    __syncthreads();
    if (tid == 0) out[0] = (red[0] + red[1] + red[2] + red[3]) * (1.0f / (float)(NB * (size_t)CC));
}

extern "C" void kernel_launch(void* const* d_in, const int* in_sizes, int n_in,
                              void* d_out, int out_size, void* d_ws, size_t ws_size,
                              hipStream_t stream) {
    const float* det = (const float*)d_in[0];
    const float* sr  = (const float*)d_in[1];
    float* gram     = (float*)d_ws;                       // 16 * 512 * 512 f32 = 16.78 MB
    float* invn     = gram + (size_t)NGRAM * CC;
    float* partials = invn + NGRAM * C_CH;
    float* out      = (float*)d_out;

    hipMemsetAsync(gram, 0, (size_t)NGRAM * CC * sizeof(float), stream);
    gram_kernel<<<GRID, 256, 0, stream>>>(det, sr, gram);
    norm_kernel<<<NGRAM, C_CH, 0, stream>>>(gram, invn);
    loss_kernel<<<LOSS_BLOCKS, 256, 0, stream>>>(gram, invn, partials);
    final_kernel<<<1, 256, 0, stream>>>(partials, out);
}

// Round 7
// 249.734 us; speedup vs baseline: 2.3929x; 2.3929x over previous
//
#include <hip/hip_runtime.h>
#include <hip/hip_bf16.h>

#define C_CH 512
#define HW 16384
#define NB 8
#define TILE 128
#define BK 32                    // f32 k-elements per K-step
#define NTB 4                    // C_CH / TILE
#define NTILES 10                // upper-triangular 128^2 tiles
#define KSPLIT 8
#define KCHUNK (HW / KSPLIT)     // 2048
#define KSTEPS (KCHUNK / BK)     // 64 (even; loop steps by 2)
#define NGRAM 16
#define CC (C_CH * C_CH)
#define LOSS_BLOCKS 1024
#define GRID (NGRAM * KSPLIT * NTILES)   // 1280 = 8 * 160
#define PANEL_V8 (TILE * BK / 8)         // 512 bf16x8 slots = 8 KiB

typedef float f32x4 __attribute__((ext_vector_type(4)));
typedef float f32x8 __attribute__((ext_vector_type(8)));
typedef __bf16 bf16x8 __attribute__((ext_vector_type(8)));

// raw barrier: drains LDS ops only; in-flight global loads SURVIVE the barrier
// (__syncthreads would emit s_waitcnt vmcnt(0) lgkmcnt(0), force-draining the
// depth-2 register pipeline every K-step)
#define BAR()                                                       \
    do {                                                            \
        asm volatile("s_waitcnt lgkmcnt(0)" ::: "memory");          \
        __builtin_amdgcn_s_barrier();                               \
    } while (0)

// LDS slot for (row R, k-chunk c in 0..3): zero-conflict pattern (measured R4/R5).
__device__ __forceinline__ int slot_of(int R, int c) {
    return (R >> 1) * 8 + ((((R & 1) << 2) + c) ^ ((R >> 1) & 7));
}

// Gram SYRK: 128x128 triangular tiles, 4 waves (2x2), bf16 LDS double-buffer,
// DEPTH-2 reg-staged pipeline; WRITE of set X waits (counted vmcnt) only on X's
// loads issued a full iteration earlier, newer set stays in flight across BAR.
__global__ __launch_bounds__(256, 2) void gram_kernel(const float* __restrict__ det,
                                                      const float* __restrict__ sr,
                                                      float* __restrict__ gram) {
    // grouped chunked XCD swizzle: all tiles/ksplits of one g on one XCD -> the
    // 4x panel re-reads hit that XCD's L2
    const int lbid = ((int)blockIdx.x & 7) * (GRID / 8) + ((int)blockIdx.x >> 3);
    const int t = lbid % NTILES;
    const int gk = lbid / NTILES;        // = g*KSPLIT + ks
    const int ks = gk & (KSPLIT - 1);
    const int g = gk >> 3;
    const int tensor = g >> 3, b = g & 7;

    int ti = 0, tt = t;
    while (tt >= NTB - ti) { tt -= NTB - ti; ++ti; }
    const int tj = ti + tt;
    const bool diag = (ti == tj);

    const float* F = (tensor ? sr : det) + (size_t)b * C_CH * HW;
    const float* Abase = F + (size_t)(ti * TILE) * HW + ks * KCHUNK;
    const float* Bbase = F + (size_t)(tj * TILE) * HW + ks * KCHUNK;

    __shared__ bf16x8 lds[4 * PANEL_V8];   // [buf0 A|B][buf1 A|B] = 32 KiB

    const int tid = threadIdx.x;
    const int lane = tid & 63;
    const int wid = tid >> 6;
    const int wr = wid >> 1, wc = wid & 1;   // 2x2 waves -> per-wave 64x64

    // staging: panel = 128 rows x 4 chunks(8 f32) = 512 chunks / 256 thr = 2 each
    int goff[2], lslot[2];
    #pragma unroll
    for (int q = 0; q < 2; ++q) {
        int c = q * 256 + tid;
        int r = c >> 2, ch = c & 3;
        goff[q] = r * HW + ch * 8;
        lslot[q] = slot_of(r, ch);
    }

    // two named register sets (no runtime indexing -> no scratch)
    f32x8 a0[2], b0[2], a1[2], b1[2];
    auto LOAD0 = [&](int kt) {
        const int ko = kt * BK;
        #pragma unroll
        for (int q = 0; q < 2; ++q) a0[q] = *(const f32x8*)(Abase + goff[q] + ko);
        if (!diag) {
            #pragma unroll
            for (int q = 0; q < 2; ++q) b0[q] = *(const f32x8*)(Bbase + goff[q] + ko);
        }
    };
    auto LOAD1 = [&](int kt) {
        const int ko = kt * BK;
        #pragma unroll
        for (int q = 0; q < 2; ++q) a1[q] = *(const f32x8*)(Abase + goff[q] + ko);
        if (!diag) {
            #pragma unroll
            for (int q = 0; q < 2; ++q) b1[q] = *(const f32x8*)(Bbase + goff[q] + ko);
        }
    };
    auto WRITE0 = [&]() {            // set0 -> buf0
        bf16x8* As = lds;
        #pragma unroll
        for (int q = 0; q < 2; ++q) {
            bf16x8 h;
            #pragma unroll
            for (int i = 0; i < 8; ++i) h[i] = (__bf16)a0[q][i];
            As[lslot[q]] = h;
        }
        if (!diag) {
            bf16x8* Bs = As + PANEL_V8;
            #pragma unroll
            for (int q = 0; q < 2; ++q) {
                bf16x8 h;
                #pragma unroll
                for (int i = 0; i < 8; ++i) h[i] = (__bf16)b0[q][i];
                Bs[lslot[q]] = h;
            }
        }
    };
    auto WRITE1 = [&]() {            // set1 -> buf1
        bf16x8* As = lds + 2 * PANEL_V8;
        #pragma unroll
        for (int q = 0; q < 2; ++q) {
            bf16x8 h;
            #pragma unroll
            for (int i = 0; i < 8; ++i) h[i] = (__bf16)a1[q][i];
            As[lslot[q]] = h;
        }
        if (!diag) {
            bf16x8* Bs = As + PANEL_V8;
            #pragma unroll
            for (int q = 0; q < 2; ++q) {
                bf16x8 h;
                #pragma unroll
                for (int i = 0; i < 8; ++i) h[i] = (__bf16)b1[q][i];
                Bs[lslot[q]] = h;
            }
        }
    };

    f32x4 acc[4][4] = {};
    const int kg = lane >> 4;            // k-chunk of this lane's fragment
    const int l15 = lane & 15;
    auto COMPUTE = [&](const bf16x8* As) {
        const bf16x8* Bs = diag ? As : As + PANEL_V8;
        bf16x8 af[4], bfr[4];
        #pragma unroll
        for (int m = 0; m < 4; ++m) {
            int R = wr * 64 + m * 16 + l15;
            af[m] = As[slot_of(R, kg)];
        }
        #pragma unroll
        for (int n = 0; n < 4; ++n) {
            int R = wc * 64 + n * 16 + l15;
            bfr[n] = Bs[slot_of(R, kg)];
        }
        __builtin_amdgcn_s_setprio(1);
        #pragma unroll
        for (int m = 0; m < 4; ++m)
            #pragma unroll
            for (int n = 0; n < 4; ++n)
                if (!diag || (wc * 64 + n * 16 + 16 > wr * 64 + m * 16))
                    acc[m][n] = __builtin_amdgcn_mfma_f32_16x16x32_bf16(af[m], bfr[n], acc[m][n], 0, 0, 0);
        __builtin_amdgcn_s_setprio(0);
    };

    // prologue: issue tiles 0 and 1; WRITE0 waits (counted) only on set0's loads
    LOAD0(0);
    LOAD1(1);
    WRITE0();
    BAR();

    #pragma unroll 1
    for (int kt = 0; kt < KSTEPS; kt += 2) {
        // even step: compute buf0 (tile kt); write tile kt+1 (set1, in flight since kt-1)
        if (kt + 2 < KSTEPS) LOAD0(kt + 2);
        COMPUTE(lds);
        WRITE1();                         // vmcnt counted: set0's loads stay in flight
        BAR();
        // odd step: compute buf1 (tile kt+1); write tile kt+2 (set0)
        if (kt + 3 < KSTEPS) LOAD1(kt + 3);
        COMPUTE(lds + 2 * PANEL_V8);
        if (kt + 2 < KSTEPS) WRITE0();
        BAR();
    }

    // epilogue: C/D layout col=lane&15, row=(lane>>4)*4+j; skip below-diag frags
    float* gout = gram + (size_t)g * CC;
    const int rb = ti * TILE + wr * 64 + (kg << 2);
    const int cb = tj * TILE + wc * 64 + l15;
    #pragma unroll
    for (int m = 0; m < 4; ++m)
        #pragma unroll
        for (int n = 0; n < 4; ++n) {
            if (diag && (wc * 64 + n * 16 + 16 <= wr * 64 + m * 16)) continue;
            #pragma unroll
            for (int j = 0; j < 4; ++j)
                atomicAdd(&gout[(size_t)(rb + m * 16 + j) * C_CH + cb + n * 16], acc[m][n][j]);
        }
}

__global__ void norm_kernel(const float* __restrict__ gram, float* __restrict__ invn) {
    const int g = blockIdx.x, c = threadIdx.x;
    float v = gram[(size_t)g * CC + (size_t)c * C_CH + c];
    invn[g * C_CH + c] = 1.0f / sqrtf(v);
}

__global__ __launch_bounds__(256) void loss_kernel(const float* __restrict__ gram,
                                                   const float* __restrict__ invn,
                                                   float* __restrict__ partials) {
    const int tid = threadIdx.x;
    float s = 0.f;
    for (int idx = blockIdx.x * 256 + tid; idx < NB * CC; idx += LOSS_BLOCKS * 256) {
        int b = idx >> 18;
        int c = (idx >> 9) & 511;
        int d = idx & 511;
        int cc = c, dd = d;
        if (dd < cc) { int tmp = cc; cc = dd; dd = tmp; }   // upper triangle stored
        float gd = gram[(size_t)b * CC + (size_t)cc * C_CH + dd];
        float gs = gram[(size_t)(8 + b) * CC + (size_t)cc * C_CH + dd];
        float sd = gd * invn[b * C_CH + c] * invn[b * C_CH + d];
        float ss = gs * invn[(8 + b) * C_CH + c] * invn[(8 + b) * C_CH + d];
        float diff = sd - ss;
        s += diff * diff;
    }
    #pragma unroll
    for (int off = 32; off > 0; off >>= 1) s += __shfl_down(s, off, 64);
    __shared__ float red[4];
    if ((tid & 63) == 0) red[tid >> 6] = s;
    __syncthreads();
    if (tid == 0) partials[blockIdx.x] = red[0] + red[1] + red[2] + red[3];
}

__global__ void final_kernel(const float* __restrict__ partials, float* __restrict__ out) {
    const int tid = threadIdx.x;  // 256
    float s = 0.f;
    for (int i = tid; i < LOSS_BLOCKS; i += 256) s += partials[i];
    #pragma unroll
    for (int off = 32; off > 0; off >>= 1) s += __shfl_down(s, off, 64);
    __shared__ float red[4];
    if ((tid & 63) == 0) red[tid >> 6] = s;
    __syncthreads();
    if (tid == 0) out[0] = (red[0] + red[1] + red[2] + red[3]) * (1.0f / (float)(NB * (size_t)CC));
}

extern "C" void kernel_launch(void* const* d_in, const int* in_sizes, int n_in,
                              void* d_out, int out_size, void* d_ws, size_t ws_size,
                              hipStream_t stream) {
    const float* det = (const float*)d_in[0];
    const float* sr  = (const float*)d_in[1];
    float* gram     = (float*)d_ws;                       // 16 * 512 * 512 f32 = 16.78 MB
    float* invn     = gram + (size_t)NGRAM * CC;
    float* partials = invn + NGRAM * C_CH;
    float* out      = (float*)d_out;

    hipMemsetAsync(gram, 0, (size_t)NGRAM * CC * sizeof(float), stream);
    gram_kernel<<<GRID, 256, 0, stream>>>(det, sr, gram);
    norm_kernel<<<NGRAM, C_CH, 0, stream>>>(gram, invn);
    loss_kernel<<<LOSS_BLOCKS, 256, 0, stream>>>(gram, invn, partials);
    final_kernel<<<1, 256, 0, stream>>>(partials, out);
}